// Round 8
// baseline (145.303 us; speedup 1.0000x reference)
//
#include <hip/hip_runtime.h>

#define N_PTS  2048
#define BATCH  64
#define NSLICE 16
#define SLICE  (N_PTS / NSLICE)   // 128 search pts per block
#define P      8                  // query points per thread (8*256 = all 2048)
#define BLK    256
#define NGROUP (2 * BATCH)        // (dir, batch) groups

static_assert(P * BLK == N_PTS, "each block covers all queries of its (b,dir)");
static_assert(SLICE <= BLK, "one staging point per thread");

// order-preserving float<->int key for signed-int atomicMin (fallback path)
__device__ __forceinline__ int fkey(float v) {
    int b = __float_as_int(v);
    return b >= 0 ? b : b ^ 0x7fffffff;
}
__device__ __forceinline__ float funkey(int b) {
    return __int_as_float(b >= 0 ? b : b ^ 0x7fffffff);
}

// ---------------------------------------------------------------------------
// K1: partial chamfer mins ONLY.  grid (NSLICE=16, BATCH, 2), block 256.
//
// Round-7 post-mortem: K1 pinned at 55.7us = 34us VALU + 26us LDS-return,
// additive; compiler sank the LDS prefetch rotation (VGPR stayed 40).
// The fix is structural, not scheduling: the search point is WAVE-UNIFORM,
// so reading it through LDS pays a pointless 64-lane x 16B VGPR writeback
// per instr (the 26us wall).  Scalar loads (s_load_dwordx4: uniform addr =
// blockIdx + loop counter on __restrict__ input) put it in SGPRs once, on
// the SMEM pipe -- LDS traffic drops to the 1-float-per-point qsq read
// (~5us, overlappable), and address math moves to SALU.  FMA operand
// budget: fmaf(pm.x[v], qv.x[s], qsq[v]) = 1 SGPR per instr, legal.
// v_min3_f32 merges 2 points per min: 4.5 VALU ops/pair -> 30.6us floor.
// Rotation with (j+4)&(SLICE-1) wrap keeps the last prefetch in-bounds.
// Round-5 lesson: NOTHING but the hot loop lives in this kernel.
// ---------------------------------------------------------------------------
template <bool ATOMIC>
__global__ __launch_bounds__(BLK, 4) void chamfer_partial(
        const float4* __restrict__ p,
        const float4* __restrict__ q,
        float* __restrict__ wpart,   // plain: [NGROUP][NSLICE][N_PTS] f32
                                     // atomic: [NGROUP][N_PTS] int keys
        float* __restrict__ out) {
    __shared__ float4 sQs4[SLICE / 4];  // 512 B: |q|^2 packed 4 per float4

    const int tid = threadIdx.x;
    const int s   = blockIdx.x;
    const int b   = blockIdx.y;
    const int dir = blockIdx.z;
    const int g   = dir * BATCH + b;
    const float4* __restrict__ A  = dir ? q : p;   // query side
    const float4* __restrict__ Bm = dir ? p : q;   // search side
    const float4* __restrict__ Ab = A  + (size_t)b * N_PTS;
    const float4* __restrict__ Bb = Bm + (size_t)b * N_PTS + s * SLICE;

    if (s == 0 && b == 0 && dir == 0 && tid == 0) out[0] = 0.0f;

    if (tid < SLICE) {   // stage |q|^2 only (coalesced float4 read)
        const float4 v = Bb[tid];
        ((float*)sQs4)[tid] = v.x * v.x + v.y * v.y + v.z * v.z + v.w * v.w;
    }
    __syncthreads();

    float4 pm[P];   // -2 * query point
    float  mn[P];
#pragma unroll
    for (int k = 0; k < P; ++k) {
        const float4 pv = Ab[tid + k * BLK];
        pm[k] = make_float4(-2.0f * pv.x, -2.0f * pv.y, -2.0f * pv.z, -2.0f * pv.w);
        mn[k] = 3.4e38f;
    }

    // depth-1 rotation; wave-uniform point loads (expected s_load_dwordx4)
    float4 nq0 = Bb[0], nq1 = Bb[1], nq2 = Bb[2], nq3 = Bb[3];
    float4 nqs = sQs4[0];
#pragma unroll 1
    for (int j = 0; j < SLICE; j += 4) {
        const float4 q0 = nq0, q1 = nq1, q2 = nq2, q3 = nq3;
        const float4 qs = nqs;
        const int jn = (j + 4) & (SLICE - 1);   // wraps to 0 on last iter (unused)
        nq0 = Bb[jn + 0]; nq1 = Bb[jn + 1]; nq2 = Bb[jn + 2]; nq3 = Bb[jn + 3];
        nqs = sQs4[jn >> 2];
#pragma unroll
        for (int k = 0; k < P; ++k) {
            float t0 = fmaf(pm[k].x, q0.x, qs.x);
            t0 = fmaf(pm[k].y, q0.y, t0);
            t0 = fmaf(pm[k].z, q0.z, t0);
            t0 = fmaf(pm[k].w, q0.w, t0);
            float t1 = fmaf(pm[k].x, q1.x, qs.y);
            t1 = fmaf(pm[k].y, q1.y, t1);
            t1 = fmaf(pm[k].z, q1.z, t1);
            t1 = fmaf(pm[k].w, q1.w, t1);
            asm("v_min3_f32 %0, %0, %1, %2" : "+v"(mn[k]) : "v"(t0), "v"(t1));
            float t2 = fmaf(pm[k].x, q2.x, qs.z);
            t2 = fmaf(pm[k].y, q2.y, t2);
            t2 = fmaf(pm[k].z, q2.z, t2);
            t2 = fmaf(pm[k].w, q2.w, t2);
            float t3 = fmaf(pm[k].x, q3.x, qs.w);
            t3 = fmaf(pm[k].y, q3.y, t3);
            t3 = fmaf(pm[k].z, q3.z, t3);
            t3 = fmaf(pm[k].w, q3.w, t3);
            asm("v_min3_f32 %0, %0, %1, %2" : "+v"(mn[k]) : "v"(t2), "v"(t3));
        }
    }

    // epilogue: fold |p|^2 back in (pm.pm = 4 p.p, saves 8 live VGPRs)
    if (ATOMIC) {
        int* wi = (int*)wpart + (size_t)g * N_PTS;
#pragma unroll
        for (int k = 0; k < P; ++k) {
            const float4 m = pm[k];
            const float psq = 0.25f * (m.x * m.x + m.y * m.y + m.z * m.z + m.w * m.w);
            atomicMin(wi + tid + k * BLK, fkey(mn[k] + psq));
        }
    } else {
        float* wf = wpart + ((size_t)g * NSLICE + s) * N_PTS;
#pragma unroll
        for (int k = 0; k < P; ++k) {
            const float4 m = pm[k];
            const float psq = 0.25f * (m.x * m.x + m.y * m.y + m.z * m.z + m.w * m.w);
            wf[tid + k * BLK] = mn[k] + psq;
        }
    }
}

// ---------------------------------------------------------------------------
// K2: merge slice partials + jet term + final sum.  grid (8, BATCH, 2) =
// 1024 blocks, 256 thr.  Each 64-lane group merges 4 slices for 64
// float4-queries (coalesced 1KiB loads, 4-deep independent), groups combine
// via LDS.  4x the blocks and 1/4 the latency chain of round-7's K2.
// ---------------------------------------------------------------------------
template <bool ATOMIC>
__global__ __launch_bounds__(BLK) void chamfer_finish(
        const float4* __restrict__ p,
        const float4* __restrict__ q,
        const float* __restrict__ wpart,
        float* __restrict__ out) {
    __shared__ float4 sm[4][64];   // 4 KB
    __shared__ float4 wacc[BLK / 64];
    const int tid  = threadIdx.x;
    const int l    = tid & 63;     // lane within 64-group
    const int grp  = tid >> 6;     // which 4-slice bundle
    const int b    = blockIdx.y;
    const int dir  = blockIdx.z;
    const int g    = dir * BATCH + b;
    const int qi4  = blockIdx.x * 64 + l;   // float4-granular query index

    if (ATOMIC) {
        if (grp == 0) {
            const int4 v = ((const int4*)wpart)[(size_t)g * (N_PTS / 4) + qi4];
            float acc = funkey(v.x) + funkey(v.y) + funkey(v.z) + funkey(v.w);
#pragma unroll
            for (int off = 32; off > 0; off >>= 1) acc += __shfl_down(acc, off, 64);
            if (l == 0) atomicAdd(out, acc);
        }
    } else {
        const float4* wf = (const float4*)wpart + (size_t)g * NSLICE * (N_PTS / 4);
        float4 m = wf[(size_t)(grp * 4) * (N_PTS / 4) + qi4];
#pragma unroll
        for (int s2 = 1; s2 < 4; ++s2) {
            const float4 v = wf[(size_t)(grp * 4 + s2) * (N_PTS / 4) + qi4];
            m.x = fminf(m.x, v.x); m.y = fminf(m.y, v.y);
            m.z = fminf(m.z, v.z); m.w = fminf(m.w, v.w);
        }
        sm[grp][l] = m;
        __syncthreads();
        if (grp == 0) {
            const float4 m1 = sm[1][l], m2 = sm[2][l], m3 = sm[3][l];
            m.x = fminf(fminf(m.x, m1.x), fminf(m2.x, m3.x));
            m.y = fminf(fminf(m.y, m1.y), fminf(m2.y, m3.y));
            m.z = fminf(fminf(m.z, m1.z), fminf(m2.z, m3.z));
            m.w = fminf(fminf(m.w, m1.w), fminf(m2.w, m3.w));
            float acc = (m.x + m.y) + (m.z + m.w);
#pragma unroll
            for (int off = 32; off > 0; off >>= 1) acc += __shfl_down(acc, off, 64);
            if (l == 0) atomicAdd(out, acc);
        }
    }

    // ---- jet term: blocks (x==0, dir==0), one per batch ----
    if (dir == 0 && blockIdx.x == 0) {
        const float4* __restrict__ Pb = p + (size_t)b * N_PTS;
        const float4* __restrict__ Qb = q + (size_t)b * N_PTS;
        float ax = 0.f, ay = 0.f, az = 0.f, aw = 0.f;
        for (int j = tid; j < N_PTS; j += BLK) {
            const float4 pv = Pb[j];
            const float4 qv = Qb[j];
            ax += pv.x - qv.x;
            ay += pv.y - qv.y;
            az += pv.z - qv.z;
            aw += pv.w - qv.w;
        }
#pragma unroll
        for (int off = 32; off > 0; off >>= 1) {
            ax += __shfl_down(ax, off, 64);
            ay += __shfl_down(ay, off, 64);
            az += __shfl_down(az, off, 64);
            aw += __shfl_down(aw, off, 64);
        }
        if (l == 0) wacc[grp] = make_float4(ax, ay, az, aw);
        __syncthreads();   // block-uniform branch: safe
        if (tid == 0) {
            float dx = 0.f, dy = 0.f, dz = 0.f, dw = 0.f;
#pragma unroll
            for (int w = 0; w < BLK / 64; ++w) {
                dx += wacc[w].x; dy += wacc[w].y; dz += wacc[w].z; dw += wacc[w].w;
            }
            atomicAdd(out, dx * dx + dy * dy + dz * dz + dw * dw);
        }
    }
}

extern "C" void kernel_launch(void* const* d_in, const int* in_sizes, int n_in,
                              void* d_out, int out_size, void* d_ws, size_t ws_size,
                              hipStream_t stream) {
    const float4* p = (const float4*)d_in[0];
    const float4* q = (const float4*)d_in[1];
    float* out = (float*)d_out;
    float* ws  = (float*)d_ws;

    const size_t part_plain  = (size_t)NGROUP * NSLICE * N_PTS * sizeof(float); // 16 MB
    const size_t part_atomic = (size_t)NGROUP * N_PTS * sizeof(int);            // 1 MB

    if (ws_size >= part_plain) {
        // deterministic plain-store path: 2 dispatches, no memset
        chamfer_partial<false><<<dim3(NSLICE, BATCH, 2), BLK, 0, stream>>>(p, q, ws, out);
        chamfer_finish<false><<<dim3(8, BATCH, 2), BLK, 0, stream>>>(p, q, ws, out);
    } else {
        // compact 1 MB fallback: atomicMin on order-preserving int keys
        hipMemsetAsync(ws, 0x7F, part_atomic, stream);  // +3.39e38 keys
        chamfer_partial<true><<<dim3(NSLICE, BATCH, 2), BLK, 0, stream>>>(p, q, ws, out);
        chamfer_finish<true><<<dim3(8, BATCH, 2), BLK, 0, stream>>>(p, q, ws, out);
    }
}

// Round 11
// 116.299 us; speedup vs baseline: 1.2494x; 1.2494x over previous
//
#include <hip/hip_runtime.h>

#define N_PTS  2048
#define BATCH  64
#define NSLICE 16
#define SLICE  (N_PTS / NSLICE)   // 128 search pts per block
#define P      16                 // query points per thread (16*128 = all 2048)
#define BLK    128                // 2 waves per block
#define NGROUP (2 * BATCH)        // (dir, batch) groups
#define QBLK4  (N_PTS / 4 / 256)  // K2 x-split over float4 queries = 2

static_assert(P * BLK == N_PTS, "each block covers all queries of its (b,dir)");
static_assert(SLICE == BLK, "staging assumes one point per thread");

// order-preserving float<->int key for signed-int atomicMin (fallback path)
__device__ __forceinline__ int fkey(float v) {
    int b = __float_as_int(v);
    return b >= 0 ? b : b ^ 0x7fffffff;
}
__device__ __forceinline__ float funkey(int b) {
    return __int_as_float(b >= 0 ? b : b ^ 0x7fffffff);
}

// ---------------------------------------------------------------------------
// K1: partial chamfer mins ONLY.  grid (NSLICE=16, BATCH, 2), block 128.
//
// Round-8 post-mortem: SMEM-broadcast of search points regressed (SGPR 48,
// LDS 512B prove it landed; 78us, real VALU ~40%): s_load shares lgkmcnt
// with DS, returns out-of-order -> per-iteration lgkmcnt(0) drains kill the
// rotation.  Search side goes back to LDS (round-6/7 structure, 55.7us).
//
// The two measured walls there: VALU ~31us (4.5 ops/pair with v_min3) and
// LDS-return 26us (waves x 5 ds_read_b128/iter x 12cyc / CU), additive.
// LDS wall scales as 1/P: P=16 (BLK=128, 2 waves, same 2048-block grid)
// halves it to ~13us.  pm[16]+mn[16]+q regs ~ 100 VGPR live:
// __launch_bounds__(128,4) caps the allocator at 128 (4-waves/SIMD cliff,
// m69) -- headroom, no round-2/8-style spill.  8 blocks/CU resident.
// Round-5 lesson: NOTHING but the hot loop lives in this kernel.
// ---------------------------------------------------------------------------
template <bool ATOMIC>
__global__ __launch_bounds__(BLK, 4) void chamfer_partial(
        const float4* __restrict__ p,
        const float4* __restrict__ q,
        float* __restrict__ wpart,   // plain: [NGROUP][NSLICE][N_PTS] f32
                                     // atomic: [NGROUP][N_PTS] int keys
        float* __restrict__ out) {
    __shared__ float4 sQ[SLICE];        // 2 KB: search-side points
    __shared__ float4 sQs4[SLICE / 4];  // 512 B: |q|^2 packed 4 per float4

    const int tid = threadIdx.x;
    const int s   = blockIdx.x;
    const int b   = blockIdx.y;
    const int dir = blockIdx.z;
    const int g   = dir * BATCH + b;
    const float4* __restrict__ A  = dir ? q : p;   // query side
    const float4* __restrict__ Bm = dir ? p : q;   // search side
    const float4* __restrict__ Ab = A  + (size_t)b * N_PTS;
    const float4* __restrict__ Bb = Bm + (size_t)b * N_PTS + s * SLICE;

    if (s == 0 && b == 0 && dir == 0 && tid == 0) out[0] = 0.0f;

    {   // stage the slice: one point per thread, coalesced
        const float4 v = Bb[tid];
        sQ[tid] = v;
        ((float*)sQs4)[tid] = v.x * v.x + v.y * v.y + v.z * v.z + v.w * v.w;
    }
    __syncthreads();

    float4 pm[P];   // -2 * query point
    float  mn[P];
#pragma unroll
    for (int k = 0; k < P; ++k) {
        const float4 pv = Ab[tid + k * BLK];
        pm[k] = make_float4(-2.0f * pv.x, -2.0f * pv.y, -2.0f * pv.z, -2.0f * pv.w);
        mn[k] = 3.4e38f;
    }

#pragma unroll 1
    for (int j = 0; j < SLICE; j += 4) {
        const float4 qs = sQs4[j >> 2];
        const float4 q0 = sQ[j + 0];
        const float4 q1 = sQ[j + 1];
        const float4 q2 = sQ[j + 2];
        const float4 q3 = sQ[j + 3];
#pragma unroll
        for (int k = 0; k < P; ++k) {
            float t0 = fmaf(pm[k].x, q0.x, qs.x);
            t0 = fmaf(pm[k].y, q0.y, t0);
            t0 = fmaf(pm[k].z, q0.z, t0);
            t0 = fmaf(pm[k].w, q0.w, t0);
            float t1 = fmaf(pm[k].x, q1.x, qs.y);
            t1 = fmaf(pm[k].y, q1.y, t1);
            t1 = fmaf(pm[k].z, q1.z, t1);
            t1 = fmaf(pm[k].w, q1.w, t1);
            asm("v_min3_f32 %0, %0, %1, %2" : "+v"(mn[k]) : "v"(t0), "v"(t1));
            float t2 = fmaf(pm[k].x, q2.x, qs.z);
            t2 = fmaf(pm[k].y, q2.y, t2);
            t2 = fmaf(pm[k].z, q2.z, t2);
            t2 = fmaf(pm[k].w, q2.w, t2);
            float t3 = fmaf(pm[k].x, q3.x, qs.w);
            t3 = fmaf(pm[k].y, q3.y, t3);
            t3 = fmaf(pm[k].z, q3.z, t3);
            t3 = fmaf(pm[k].w, q3.w, t3);
            asm("v_min3_f32 %0, %0, %1, %2" : "+v"(mn[k]) : "v"(t2), "v"(t3));
        }
    }

    // epilogue: fold |p|^2 back in (pm.pm = 4 p.p, saves 16 live VGPRs)
    if (ATOMIC) {
        int* wi = (int*)wpart + (size_t)g * N_PTS;
#pragma unroll
        for (int k = 0; k < P; ++k) {
            const float4 m = pm[k];
            const float psq = 0.25f * (m.x * m.x + m.y * m.y + m.z * m.z + m.w * m.w);
            atomicMin(wi + tid + k * BLK, fkey(mn[k] + psq));
        }
    } else {
        float* wf = wpart + ((size_t)g * NSLICE + s) * N_PTS;
#pragma unroll
        for (int k = 0; k < P; ++k) {
            const float4 m = pm[k];
            const float psq = 0.25f * (m.x * m.x + m.y * m.y + m.z * m.z + m.w * m.w);
            wf[tid + k * BLK] = mn[k] + psq;
        }
    }
}

// ---------------------------------------------------------------------------
// K2: merge slice partials + jet term + final sum.  (round-7 version, 256
// threads, grid (2, BATCH, 2) = 256 blocks; each thread merges 4 consecutive
// queries across 16 slices with float4 loads, coalesced 1KiB/wave-instr.)
// ---------------------------------------------------------------------------
template <bool ATOMIC>
__global__ __launch_bounds__(256) void chamfer_finish(
        const float4* __restrict__ p,
        const float4* __restrict__ q,
        const float* __restrict__ wpart,
        float* __restrict__ out) {
    __shared__ float wred[4];
    __shared__ float4 wacc[4];
    const int tid  = threadIdx.x;
    const int qi4  = blockIdx.x * 256 + tid;   // float4-granular query index
    const int b    = blockIdx.y;
    const int dir  = blockIdx.z;
    const int g    = dir * BATCH + b;
    const int lane = tid & 63;
    const int wid  = tid >> 6;

    float acc;
    if (ATOMIC) {
        const int4 v = ((const int4*)wpart)[(size_t)g * (N_PTS / 4) + qi4];
        acc = funkey(v.x) + funkey(v.y) + funkey(v.z) + funkey(v.w);
    } else {
        const float4* wf = (const float4*)wpart + (size_t)g * NSLICE * (N_PTS / 4);
        float4 m = wf[qi4];
#pragma unroll
        for (int s2 = 1; s2 < NSLICE; ++s2) {
            const float4 v = wf[(size_t)s2 * (N_PTS / 4) + qi4];
            m.x = fminf(m.x, v.x); m.y = fminf(m.y, v.y);
            m.z = fminf(m.z, v.z); m.w = fminf(m.w, v.w);
        }
        acc = (m.x + m.y) + (m.z + m.w);
    }

#pragma unroll
    for (int off = 32; off > 0; off >>= 1) acc += __shfl_down(acc, off, 64);
    if (lane == 0) wred[wid] = acc;
    __syncthreads();
    if (tid == 0) {
        atomicAdd(out, wred[0] + wred[1] + wred[2] + wred[3]);
    }

    // ---- jet term: blocks (x==0, dir==0), one per batch ----
    if (dir == 0 && blockIdx.x == 0) {
        const float4* __restrict__ Pb = p + (size_t)b * N_PTS;
        const float4* __restrict__ Qb = q + (size_t)b * N_PTS;
        float ax = 0.f, ay = 0.f, az = 0.f, aw = 0.f;
        for (int j = tid; j < N_PTS; j += 256) {
            const float4 pv = Pb[j];
            const float4 qv = Qb[j];
            ax += pv.x - qv.x;
            ay += pv.y - qv.y;
            az += pv.z - qv.z;
            aw += pv.w - qv.w;
        }
#pragma unroll
        for (int off = 32; off > 0; off >>= 1) {
            ax += __shfl_down(ax, off, 64);
            ay += __shfl_down(ay, off, 64);
            az += __shfl_down(az, off, 64);
            aw += __shfl_down(aw, off, 64);
        }
        if (lane == 0) wacc[wid] = make_float4(ax, ay, az, aw);
        __syncthreads();   // block-uniform branch: safe
        if (tid == 0) {
            float dx = 0.f, dy = 0.f, dz = 0.f, dw = 0.f;
#pragma unroll
            for (int w = 0; w < 4; ++w) {
                dx += wacc[w].x; dy += wacc[w].y; dz += wacc[w].z; dw += wacc[w].w;
            }
            atomicAdd(out, dx * dx + dy * dy + dz * dz + dw * dw);
        }
    }
}

extern "C" void kernel_launch(void* const* d_in, const int* in_sizes, int n_in,
                              void* d_out, int out_size, void* d_ws, size_t ws_size,
                              hipStream_t stream) {
    const float4* p = (const float4*)d_in[0];
    const float4* q = (const float4*)d_in[1];
    float* out = (float*)d_out;
    float* ws  = (float*)d_ws;

    const size_t part_plain  = (size_t)NGROUP * NSLICE * N_PTS * sizeof(float); // 16 MB
    const size_t part_atomic = (size_t)NGROUP * N_PTS * sizeof(int);            // 1 MB

    if (ws_size >= part_plain) {
        // deterministic plain-store path: 2 dispatches, no memset
        chamfer_partial<false><<<dim3(NSLICE, BATCH, 2), BLK, 0, stream>>>(p, q, ws, out);
        chamfer_finish<false><<<dim3(QBLK4, BATCH, 2), 256, 0, stream>>>(p, q, ws, out);
    } else {
        // compact 1 MB fallback: atomicMin on order-preserving int keys
        hipMemsetAsync(ws, 0x7F, part_atomic, stream);  // +3.39e38 keys
        chamfer_partial<true><<<dim3(NSLICE, BATCH, 2), BLK, 0, stream>>>(p, q, ws, out);
        chamfer_finish<true><<<dim3(QBLK4, BATCH, 2), 256, 0, stream>>>(p, q, ws, out);
    }
}

// Round 17
// 106.145 us; speedup vs baseline: 1.3689x; 1.0957x over previous
//
#include <hip/hip_runtime.h>

#define N_PTS  2048
#define BATCH  64
#define NSLICE 16
#define SLICE  (N_PTS / NSLICE)   // 128 search cols per block
#define P      8                  // rows per thread (8*256 = all 2048 rows)
#define BLK    256

static_assert(P * BLK == N_PTS, "block must cover all rows for col-final mins");
static_assert(SLICE <= BLK, "one staged point per thread");

// order-preserving float<->int key for signed-int atomicMin
__device__ __forceinline__ int fkey(float v) {
    int b = __float_as_int(v);
    return b >= 0 ? b : b ^ 0x7fffffff;
}
__device__ __forceinline__ float funkey(int b) {
    return __int_as_float(b >= 0 ? b : b ^ 0x7fffffff);
}

// ---------------------------------------------------------------------------
// K1: SYMMETRIC chamfer tile.  grid (NSLICE=16, BATCH) -- no dir axis.
//
// Round-11 insight: dist[n][m] is identical for both directions; the old
// dir=0/dir=1 passes computed every pair twice.  Here each pair is computed
// ONCE: u = |p_n - q_m|^2 via fmaf chain from (qsq_c + psq_k), feeding BOTH
// the row-min registers (v_min3 pairs) and 4 column accumulators.
// 6 VALU ops/pair, 2.75e8 pairs -> 21us VALU floor (was 31.5 at 2x pairs).
// LDS staging also halves (~12us).  Column mins: thread-local over P rows,
// then a 7-shuffle transpose-reduce (2 select steps fold c0..c3 -> one col
// per lane keyed by lane&3, then xor-4/8/16/32 butterfly), 4 LDS atomicMin
// per wave per j-iter; block spans all rows so colk is final -> plain store.
// amdgpu_waves_per_eu(4,4) pins the VGPR budget at 128: the live set is
// ~78 and rounds 6/11 proved the default heuristic squeezes to <=64 and
// AGPR-taxes the hot loop.  Round-5 lesson: only the hot loop lives here.
// ---------------------------------------------------------------------------
template <bool ATOMIC>
__global__ __launch_bounds__(BLK)
__attribute__((amdgpu_waves_per_eu(4, 4)))
void chamfer_partial(
        const float4* __restrict__ p,
        const float4* __restrict__ q,
        float* __restrict__ wrow,   // plain: [BATCH][NSLICE][N_PTS] f32
                                    // atomic: [BATCH][N_PTS] int keys
        float* __restrict__ wcol,   // [BATCH][N_PTS] f32, block-exclusive
        float* __restrict__ out) {
    __shared__ float4 sQ[SLICE];        // 2 KB
    __shared__ float4 sQs4[SLICE / 4];  // 512 B
    __shared__ int    colk[SLICE];      // 512 B

    const int tid = threadIdx.x;
    const int s   = blockIdx.x;
    const int b   = blockIdx.y;
    const float4* __restrict__ Pb = p + (size_t)b * N_PTS;
    const float4* __restrict__ Qb = q + (size_t)b * N_PTS + s * SLICE;

    if (s == 0 && b == 0 && tid == 0) out[0] = 0.0f;

    if (tid < SLICE) {   // stage col slice + |q|^2 + init col keys
        const float4 v = Qb[tid];
        sQ[tid] = v;
        ((float*)sQs4)[tid] = v.x * v.x + v.y * v.y + v.z * v.z + v.w * v.w;
        colk[tid] = 0x7FFFFFFF;
    }
    __syncthreads();

    float4 pm[P];   // -2 * row point
    float  psq[P];  // |p|^2
    float  mn[P];   // row mins (carry psq folded in)
#pragma unroll
    for (int k = 0; k < P; ++k) {
        const float4 pv = Pb[tid + k * BLK];
        psq[k] = pv.x * pv.x + pv.y * pv.y + pv.z * pv.z + pv.w * pv.w;
        pm[k]  = make_float4(-2.0f * pv.x, -2.0f * pv.y, -2.0f * pv.z, -2.0f * pv.w);
        mn[k]  = 3.4e38f;
    }

#pragma unroll 1
    for (int j = 0; j < SLICE; j += 4) {
        const float4 qs = sQs4[j >> 2];
        const float4 q0 = sQ[j + 0];
        const float4 q1 = sQ[j + 1];
        const float4 q2 = sQ[j + 2];
        const float4 q3 = sQ[j + 3];
        float c0 = 3.4e38f, c1 = 3.4e38f, c2 = 3.4e38f, c3 = 3.4e38f;
#pragma unroll
        for (int k = 0; k < P; k += 2) {
            const float4 a0 = pm[k], a1 = pm[k + 1];
            const float  e0 = psq[k], e1 = psq[k + 1];
            float u00 = fmaf(a0.x, q0.x, qs.x + e0);
            u00 = fmaf(a0.y, q0.y, u00); u00 = fmaf(a0.z, q0.z, u00); u00 = fmaf(a0.w, q0.w, u00);
            float u01 = fmaf(a0.x, q1.x, qs.y + e0);
            u01 = fmaf(a0.y, q1.y, u01); u01 = fmaf(a0.z, q1.z, u01); u01 = fmaf(a0.w, q1.w, u01);
            float u02 = fmaf(a0.x, q2.x, qs.z + e0);
            u02 = fmaf(a0.y, q2.y, u02); u02 = fmaf(a0.z, q2.z, u02); u02 = fmaf(a0.w, q2.w, u02);
            float u03 = fmaf(a0.x, q3.x, qs.w + e0);
            u03 = fmaf(a0.y, q3.y, u03); u03 = fmaf(a0.z, q3.z, u03); u03 = fmaf(a0.w, q3.w, u03);
            float u10 = fmaf(a1.x, q0.x, qs.x + e1);
            u10 = fmaf(a1.y, q0.y, u10); u10 = fmaf(a1.z, q0.z, u10); u10 = fmaf(a1.w, q0.w, u10);
            float u11 = fmaf(a1.x, q1.x, qs.y + e1);
            u11 = fmaf(a1.y, q1.y, u11); u11 = fmaf(a1.z, q1.z, u11); u11 = fmaf(a1.w, q1.w, u11);
            float u12 = fmaf(a1.x, q2.x, qs.z + e1);
            u12 = fmaf(a1.y, q2.y, u12); u12 = fmaf(a1.z, q2.z, u12); u12 = fmaf(a1.w, q2.w, u12);
            float u13 = fmaf(a1.x, q3.x, qs.w + e1);
            u13 = fmaf(a1.y, q3.y, u13); u13 = fmaf(a1.z, q3.z, u13); u13 = fmaf(a1.w, q3.w, u13);
            // row mins (2 min3 per row)
            asm("v_min3_f32 %0, %0, %1, %2" : "+v"(mn[k])     : "v"(u00), "v"(u01));
            asm("v_min3_f32 %0, %0, %1, %2" : "+v"(mn[k])     : "v"(u02), "v"(u03));
            asm("v_min3_f32 %0, %0, %1, %2" : "+v"(mn[k + 1]) : "v"(u10), "v"(u11));
            asm("v_min3_f32 %0, %0, %1, %2" : "+v"(mn[k + 1]) : "v"(u12), "v"(u13));
            // col mins (1 min3 per col per row-pair)
            asm("v_min3_f32 %0, %0, %1, %2" : "+v"(c0) : "v"(u00), "v"(u10));
            asm("v_min3_f32 %0, %0, %1, %2" : "+v"(c1) : "v"(u01), "v"(u11));
            asm("v_min3_f32 %0, %0, %1, %2" : "+v"(c2) : "v"(u02), "v"(u12));
            asm("v_min3_f32 %0, %0, %1, %2" : "+v"(c3) : "v"(u03), "v"(u13));
        }
        // wave transpose-reduce: fold 4 cols -> col (lane&3), then butterfly.
        const int l = tid & 63;
        const float sa = (l & 1) ? c0 : c1;   // send col 1-b0
        const float sb = (l & 1) ? c2 : c3;   // send col 3-b0
        const float ka = (l & 1) ? c1 : c0;   // keep col b0
        const float kb = (l & 1) ? c3 : c2;   // keep col 2+b0
        const float r0 = fminf(ka, __shfl_xor(sa, 1, 64));
        const float r1 = fminf(kb, __shfl_xor(sb, 1, 64));
        const float sc = (l & 2) ? r0 : r1;   // send the col the partner keeps
        const float kc = (l & 2) ? r1 : r0;   // keep col (l&3)
        float m = fminf(kc, __shfl_xor(sc, 2, 64));
        m = fminf(m, __shfl_xor(m, 4, 64));
        m = fminf(m, __shfl_xor(m, 8, 64));
        m = fminf(m, __shfl_xor(m, 16, 64));
        m = fminf(m, __shfl_xor(m, 32, 64));
        if (l < 4) atomicMin(&colk[j + l], fkey(m));
    }

    // row epilogue (mn already includes psq via the u-chain)
    if (ATOMIC) {
        int* wi = (int*)wrow + (size_t)b * N_PTS;
#pragma unroll
        for (int k = 0; k < P; ++k)
            atomicMin(wi + tid + k * BLK, fkey(mn[k]));
    } else {
        float* wf = wrow + ((size_t)b * NSLICE + s) * N_PTS;
#pragma unroll
        for (int k = 0; k < P; ++k)
            wf[tid + k * BLK] = mn[k];
    }

    // col epilogue: block-final (all 2048 rows seen), block-exclusive range
    __syncthreads();
    if (tid < SLICE)
        wcol[(size_t)b * N_PTS + s * SLICE + tid] = funkey(colk[tid]);
}

// ---------------------------------------------------------------------------
// K2: 16-way row merge + col sum + jet + final sum.  grid (2, BATCH), 256
// thr; float4 per thread (coalesced 1KiB/wave-instr).  ~9MB reads, ~10us.
// ---------------------------------------------------------------------------
template <bool ATOMIC>
__global__ __launch_bounds__(256) void chamfer_finish(
        const float4* __restrict__ p,
        const float4* __restrict__ q,
        const float* __restrict__ wrow,
        const float* __restrict__ wcol,
        float* __restrict__ out) {
    __shared__ float wred[4];
    __shared__ float4 wacc[4];
    const int tid  = threadIdx.x;
    const int qi4  = blockIdx.x * 256 + tid;   // float4-granular index, 0..511
    const int b    = blockIdx.y;
    const int lane = tid & 63;
    const int wid  = tid >> 6;

    float acc;
    if (ATOMIC) {
        const int4 v = ((const int4*)wrow)[(size_t)b * (N_PTS / 4) + qi4];
        acc = funkey(v.x) + funkey(v.y) + funkey(v.z) + funkey(v.w);
    } else {
        const float4* wf = (const float4*)wrow + (size_t)b * NSLICE * (N_PTS / 4);
        float4 m = wf[qi4];
#pragma unroll
        for (int s2 = 1; s2 < NSLICE; ++s2) {
            const float4 v = wf[(size_t)s2 * (N_PTS / 4) + qi4];
            m.x = fminf(m.x, v.x); m.y = fminf(m.y, v.y);
            m.z = fminf(m.z, v.z); m.w = fminf(m.w, v.w);
        }
        acc = (m.x + m.y) + (m.z + m.w);
    }
    {   // column mins (already final)
        const float4 cv = ((const float4*)wcol)[(size_t)b * (N_PTS / 4) + qi4];
        acc += (cv.x + cv.y) + (cv.z + cv.w);
    }

#pragma unroll
    for (int off = 32; off > 0; off >>= 1) acc += __shfl_down(acc, off, 64);
    if (lane == 0) wred[wid] = acc;
    __syncthreads();
    if (tid == 0) {
        atomicAdd(out, wred[0] + wred[1] + wred[2] + wred[3]);
    }

    // ---- jet term: x==0 block of each batch ----
    if (blockIdx.x == 0) {
        const float4* __restrict__ Pb = p + (size_t)b * N_PTS;
        const float4* __restrict__ Qb = q + (size_t)b * N_PTS;
        float ax = 0.f, ay = 0.f, az = 0.f, aw = 0.f;
        for (int j = tid; j < N_PTS; j += 256) {
            const float4 pv = Pb[j];
            const float4 qv = Qb[j];
            ax += pv.x - qv.x;
            ay += pv.y - qv.y;
            az += pv.z - qv.z;
            aw += pv.w - qv.w;
        }
#pragma unroll
        for (int off = 32; off > 0; off >>= 1) {
            ax += __shfl_down(ax, off, 64);
            ay += __shfl_down(ay, off, 64);
            az += __shfl_down(az, off, 64);
            aw += __shfl_down(aw, off, 64);
        }
        if (lane == 0) wacc[wid] = make_float4(ax, ay, az, aw);
        __syncthreads();   // block-uniform branch: safe
        if (tid == 0) {
            float dx = 0.f, dy = 0.f, dz = 0.f, dw = 0.f;
#pragma unroll
            for (int w = 0; w < 4; ++w) {
                dx += wacc[w].x; dy += wacc[w].y; dz += wacc[w].z; dw += wacc[w].w;
            }
            atomicAdd(out, dx * dx + dy * dy + dz * dz + dw * dw);
        }
    }
}

extern "C" void kernel_launch(void* const* d_in, const int* in_sizes, int n_in,
                              void* d_out, int out_size, void* d_ws, size_t ws_size,
                              hipStream_t stream) {
    const float4* p = (const float4*)d_in[0];
    const float4* q = (const float4*)d_in[1];
    float* out = (float*)d_out;
    float* ws  = (float*)d_ws;

    const size_t row_plain  = (size_t)BATCH * NSLICE * N_PTS;  // floats, 8 MB
    const size_t row_atomic = (size_t)BATCH * N_PTS;           // ints, 512 KB
    const size_t col_elems  = (size_t)BATCH * N_PTS;           // floats, 512 KB

    if (ws_size >= (row_plain + col_elems) * sizeof(float)) {
        // deterministic plain-store path: 2 dispatches, no memset
        float* wrow = ws;
        float* wcol = ws + row_plain;
        chamfer_partial<false><<<dim3(NSLICE, BATCH), BLK, 0, stream>>>(p, q, wrow, wcol, out);
        chamfer_finish<false><<<dim3(2, BATCH), 256, 0, stream>>>(p, q, wrow, wcol, out);
    } else {
        // compact 1 MB fallback: global atomicMin on int keys for rows
        float* wrow = ws;
        float* wcol = ws + row_atomic;
        hipMemsetAsync(wrow, 0x7F, row_atomic * sizeof(int), stream);
        chamfer_partial<true><<<dim3(NSLICE, BATCH), BLK, 0, stream>>>(p, q, wrow, wcol, out);
        chamfer_finish<true><<<dim3(2, BATCH), 256, 0, stream>>>(p, q, wrow, wcol, out);
    }
}

// Round 18
// 105.775 us; speedup vs baseline: 1.3737x; 1.0035x over previous
//
#include <hip/hip_runtime.h>

#define N_PTS  2048
#define BATCH  64
#define NSLICE 32
#define SLICE  (N_PTS / NSLICE)   // 64 search cols per block
#define P      8                  // rows per thread (8*256 = all 2048 rows)
#define BLK    256

static_assert(P * BLK == N_PTS, "block must cover all rows for col-final mins");
static_assert(SLICE <= BLK, "one staged point per thread");

// order-preserving float<->int key for signed-int atomicMin
__device__ __forceinline__ int fkey(float v) {
    int b = __float_as_int(v);
    return b >= 0 ? b : b ^ 0x7fffffff;
}
__device__ __forceinline__ float funkey(int b) {
    return __int_as_float(b >= 0 ? b : b ^ 0x7fffffff);
}

// ---------------------------------------------------------------------------
// K1: SYMMETRIC chamfer tile.  grid (NSLICE=32, BATCH) = 2048 blocks.
//
// Round-17 (first HW run of symmetric pass): 52.2us, absmax=0 (transpose-
// reduce verified), WRITE 8.7MB / FETCH 9.2MB as predicted.  But VGPR=52
// (waves_per_eu(4,4) did NOT unlock the allocator) and Occupancy 28%
// (1024 blocks = 4/CU ceiling): VALU ~23us and DS ~21us (5 data b128 +
// 7 shuffle ds_swizzle per j-iter share the LDS pipe) mostly SERIALIZE at
// 2.3 waves/SIMD.  Cure proven in round 6 (63->57 at 2x grid): NSLICE=32
// -> 2048 blocks = 8 blocks/CU (LDS only ~1.5KB, not limiting).  Also:
// __launch_bounds__(BLK,4) (round-6-proven clean) replaces waves_per_eu,
// and the butterfly drops xor32 -- lanes 0-3 AND 32-35 commit via LDS
// atomicMin (2-way same-address is free, m136), saving 1 shuffle + ~30cy
// serial chain per j-iter.  Round-5 lesson: only the hot loop lives here.
// ---------------------------------------------------------------------------
template <bool ATOMIC>
__global__ __launch_bounds__(BLK, 4) void chamfer_partial(
        const float4* __restrict__ p,
        const float4* __restrict__ q,
        float* __restrict__ wrow,   // plain: [BATCH][NSLICE][N_PTS] f32
                                    // atomic: [BATCH][N_PTS] int keys
        float* __restrict__ wcol,   // [BATCH][N_PTS] f32, block-exclusive
        float* __restrict__ out) {
    __shared__ float4 sQ[SLICE];        // 1 KB
    __shared__ float4 sQs4[SLICE / 4];  // 256 B
    __shared__ int    colk[SLICE];      // 256 B

    const int tid = threadIdx.x;
    const int s   = blockIdx.x;
    const int b   = blockIdx.y;
    const float4* __restrict__ Pb = p + (size_t)b * N_PTS;
    const float4* __restrict__ Qb = q + (size_t)b * N_PTS + s * SLICE;

    if (s == 0 && b == 0 && tid == 0) out[0] = 0.0f;

    if (tid < SLICE) {   // stage col slice + |q|^2 + init col keys
        const float4 v = Qb[tid];
        sQ[tid] = v;
        ((float*)sQs4)[tid] = v.x * v.x + v.y * v.y + v.z * v.z + v.w * v.w;
        colk[tid] = 0x7FFFFFFF;
    }
    __syncthreads();

    float4 pm[P];   // -2 * row point
    float  psq[P];  // |p|^2
    float  mn[P];   // row mins (carry psq folded in)
#pragma unroll
    for (int k = 0; k < P; ++k) {
        const float4 pv = Pb[tid + k * BLK];
        psq[k] = pv.x * pv.x + pv.y * pv.y + pv.z * pv.z + pv.w * pv.w;
        pm[k]  = make_float4(-2.0f * pv.x, -2.0f * pv.y, -2.0f * pv.z, -2.0f * pv.w);
        mn[k]  = 3.4e38f;
    }

#pragma unroll 1
    for (int j = 0; j < SLICE; j += 4) {
        const float4 qs = sQs4[j >> 2];
        const float4 q0 = sQ[j + 0];
        const float4 q1 = sQ[j + 1];
        const float4 q2 = sQ[j + 2];
        const float4 q3 = sQ[j + 3];
        float c0 = 3.4e38f, c1 = 3.4e38f, c2 = 3.4e38f, c3 = 3.4e38f;
#pragma unroll
        for (int k = 0; k < P; k += 2) {
            const float4 a0 = pm[k], a1 = pm[k + 1];
            const float  e0 = psq[k], e1 = psq[k + 1];
            float u00 = fmaf(a0.x, q0.x, qs.x + e0);
            u00 = fmaf(a0.y, q0.y, u00); u00 = fmaf(a0.z, q0.z, u00); u00 = fmaf(a0.w, q0.w, u00);
            float u01 = fmaf(a0.x, q1.x, qs.y + e0);
            u01 = fmaf(a0.y, q1.y, u01); u01 = fmaf(a0.z, q1.z, u01); u01 = fmaf(a0.w, q1.w, u01);
            float u02 = fmaf(a0.x, q2.x, qs.z + e0);
            u02 = fmaf(a0.y, q2.y, u02); u02 = fmaf(a0.z, q2.z, u02); u02 = fmaf(a0.w, q2.w, u02);
            float u03 = fmaf(a0.x, q3.x, qs.w + e0);
            u03 = fmaf(a0.y, q3.y, u03); u03 = fmaf(a0.z, q3.z, u03); u03 = fmaf(a0.w, q3.w, u03);
            float u10 = fmaf(a1.x, q0.x, qs.x + e1);
            u10 = fmaf(a1.y, q0.y, u10); u10 = fmaf(a1.z, q0.z, u10); u10 = fmaf(a1.w, q0.w, u10);
            float u11 = fmaf(a1.x, q1.x, qs.y + e1);
            u11 = fmaf(a1.y, q1.y, u11); u11 = fmaf(a1.z, q1.z, u11); u11 = fmaf(a1.w, q1.w, u11);
            float u12 = fmaf(a1.x, q2.x, qs.z + e1);
            u12 = fmaf(a1.y, q2.y, u12); u12 = fmaf(a1.z, q2.z, u12); u12 = fmaf(a1.w, q2.w, u12);
            float u13 = fmaf(a1.x, q3.x, qs.w + e1);
            u13 = fmaf(a1.y, q3.y, u13); u13 = fmaf(a1.z, q3.z, u13); u13 = fmaf(a1.w, q3.w, u13);
            // row mins (2 min3 per row)
            asm("v_min3_f32 %0, %0, %1, %2" : "+v"(mn[k])     : "v"(u00), "v"(u01));
            asm("v_min3_f32 %0, %0, %1, %2" : "+v"(mn[k])     : "v"(u02), "v"(u03));
            asm("v_min3_f32 %0, %0, %1, %2" : "+v"(mn[k + 1]) : "v"(u10), "v"(u11));
            asm("v_min3_f32 %0, %0, %1, %2" : "+v"(mn[k + 1]) : "v"(u12), "v"(u13));
            // col mins (1 min3 per col per row-pair)
            asm("v_min3_f32 %0, %0, %1, %2" : "+v"(c0) : "v"(u00), "v"(u10));
            asm("v_min3_f32 %0, %0, %1, %2" : "+v"(c1) : "v"(u01), "v"(u11));
            asm("v_min3_f32 %0, %0, %1, %2" : "+v"(c2) : "v"(u02), "v"(u12));
            asm("v_min3_f32 %0, %0, %1, %2" : "+v"(c3) : "v"(u03), "v"(u13));
        }
        // wave transpose-reduce: fold 4 cols -> col (lane&3), butterfly to
        // 32-lane halves, then BOTH halves commit (2-way LDS atomic = free).
        const int l = tid & 63;
        const float sa = (l & 1) ? c0 : c1;   // send col 1-b0
        const float sb = (l & 1) ? c2 : c3;   // send col 3-b0
        const float ka = (l & 1) ? c1 : c0;   // keep col b0
        const float kb = (l & 1) ? c3 : c2;   // keep col 2+b0
        const float r0 = fminf(ka, __shfl_xor(sa, 1, 64));
        const float r1 = fminf(kb, __shfl_xor(sb, 1, 64));
        const float sc = (l & 2) ? r0 : r1;   // send the col the partner keeps
        const float kc = (l & 2) ? r1 : r0;   // keep col (l&3)
        float m = fminf(kc, __shfl_xor(sc, 2, 64));
        m = fminf(m, __shfl_xor(m, 4, 64));
        m = fminf(m, __shfl_xor(m, 8, 64));
        m = fminf(m, __shfl_xor(m, 16, 64));
        if ((l & 31) < 4) atomicMin(&colk[j + (l & 3)], fkey(m));
    }

    // row epilogue (mn already includes psq via the u-chain)
    if (ATOMIC) {
        int* wi = (int*)wrow + (size_t)b * N_PTS;
#pragma unroll
        for (int k = 0; k < P; ++k)
            atomicMin(wi + tid + k * BLK, fkey(mn[k]));
    } else {
        float* wf = wrow + ((size_t)b * NSLICE + s) * N_PTS;
#pragma unroll
        for (int k = 0; k < P; ++k)
            wf[tid + k * BLK] = mn[k];
    }

    // col epilogue: block-final (all 2048 rows seen), block-exclusive range
    __syncthreads();
    if (tid < SLICE)
        wcol[(size_t)b * N_PTS + s * SLICE + tid] = funkey(colk[tid]);
}

// ---------------------------------------------------------------------------
// K2: 32-way row merge + col sum + jet + final sum.  grid (2, BATCH), 256
// thr; float4 per thread (coalesced 1KiB/wave-instr).  ~17MB reads, ~12us.
// ---------------------------------------------------------------------------
template <bool ATOMIC>
__global__ __launch_bounds__(256) void chamfer_finish(
        const float4* __restrict__ p,
        const float4* __restrict__ q,
        const float* __restrict__ wrow,
        const float* __restrict__ wcol,
        float* __restrict__ out) {
    __shared__ float wred[4];
    __shared__ float4 wacc[4];
    const int tid  = threadIdx.x;
    const int qi4  = blockIdx.x * 256 + tid;   // float4-granular index, 0..511
    const int b    = blockIdx.y;
    const int lane = tid & 63;
    const int wid  = tid >> 6;

    float acc;
    if (ATOMIC) {
        const int4 v = ((const int4*)wrow)[(size_t)b * (N_PTS / 4) + qi4];
        acc = funkey(v.x) + funkey(v.y) + funkey(v.z) + funkey(v.w);
    } else {
        const float4* wf = (const float4*)wrow + (size_t)b * NSLICE * (N_PTS / 4);
        float4 m = wf[qi4];
#pragma unroll
        for (int s2 = 1; s2 < NSLICE; ++s2) {
            const float4 v = wf[(size_t)s2 * (N_PTS / 4) + qi4];
            m.x = fminf(m.x, v.x); m.y = fminf(m.y, v.y);
            m.z = fminf(m.z, v.z); m.w = fminf(m.w, v.w);
        }
        acc = (m.x + m.y) + (m.z + m.w);
    }
    {   // column mins (already final)
        const float4 cv = ((const float4*)wcol)[(size_t)b * (N_PTS / 4) + qi4];
        acc += (cv.x + cv.y) + (cv.z + cv.w);
    }

#pragma unroll
    for (int off = 32; off > 0; off >>= 1) acc += __shfl_down(acc, off, 64);
    if (lane == 0) wred[wid] = acc;
    __syncthreads();
    if (tid == 0) {
        atomicAdd(out, wred[0] + wred[1] + wred[2] + wred[3]);
    }

    // ---- jet term: x==0 block of each batch ----
    if (blockIdx.x == 0) {
        const float4* __restrict__ Pb = p + (size_t)b * N_PTS;
        const float4* __restrict__ Qb = q + (size_t)b * N_PTS;
        float ax = 0.f, ay = 0.f, az = 0.f, aw = 0.f;
        for (int j = tid; j < N_PTS; j += 256) {
            const float4 pv = Pb[j];
            const float4 qv = Qb[j];
            ax += pv.x - qv.x;
            ay += pv.y - qv.y;
            az += pv.z - qv.z;
            aw += pv.w - qv.w;
        }
#pragma unroll
        for (int off = 32; off > 0; off >>= 1) {
            ax += __shfl_down(ax, off, 64);
            ay += __shfl_down(ay, off, 64);
            az += __shfl_down(az, off, 64);
            aw += __shfl_down(aw, off, 64);
        }
        if (lane == 0) wacc[wid] = make_float4(ax, ay, az, aw);
        __syncthreads();   // block-uniform branch: safe
        if (tid == 0) {
            float dx = 0.f, dy = 0.f, dz = 0.f, dw = 0.f;
#pragma unroll
            for (int w = 0; w < 4; ++w) {
                dx += wacc[w].x; dy += wacc[w].y; dz += wacc[w].z; dw += wacc[w].w;
            }
            atomicAdd(out, dx * dx + dy * dy + dz * dz + dw * dw);
        }
    }
}

extern "C" void kernel_launch(void* const* d_in, const int* in_sizes, int n_in,
                              void* d_out, int out_size, void* d_ws, size_t ws_size,
                              hipStream_t stream) {
    const float4* p = (const float4*)d_in[0];
    const float4* q = (const float4*)d_in[1];
    float* out = (float*)d_out;
    float* ws  = (float*)d_ws;

    const size_t row_plain  = (size_t)BATCH * NSLICE * N_PTS;  // floats, 16 MB
    const size_t row_atomic = (size_t)BATCH * N_PTS;           // ints, 512 KB
    const size_t col_elems  = (size_t)BATCH * N_PTS;           // floats, 512 KB

    if (ws_size >= (row_plain + col_elems) * sizeof(float)) {
        // deterministic plain-store path: 2 dispatches, no memset
        float* wrow = ws;
        float* wcol = ws + row_plain;
        chamfer_partial<false><<<dim3(NSLICE, BATCH), BLK, 0, stream>>>(p, q, wrow, wcol, out);
        chamfer_finish<false><<<dim3(2, BATCH), 256, 0, stream>>>(p, q, wrow, wcol, out);
    } else {
        // compact 1 MB fallback: global atomicMin on int keys for rows
        float* wrow = ws;
        float* wcol = ws + row_atomic;
        hipMemsetAsync(wrow, 0x7F, row_atomic * sizeof(int), stream);
        chamfer_partial<true><<<dim3(NSLICE, BATCH), BLK, 0, stream>>>(p, q, wrow, wcol, out);
        chamfer_finish<true><<<dim3(2, BATCH), 256, 0, stream>>>(p, q, wrow, wcol, out);
    }
}